// Round 4
// baseline (135.830 us; speedup 1.0000x reference)
//
#include <hip/hip_runtime.h>
#include <math.h>

constexpr int NBINS = 1025;          // 2048/2 + 1
constexpr int NROWS = 128 * 192;     // B * P

// Round-to-nearest-even float -> bf16 (finite inputs only).
__device__ inline unsigned int f2bf(float f) {
    unsigned int u = __float_as_uint(f);
    return (u + 0x7FFFu + ((u >> 16) & 1u)) >> 16;
}

// One block per (b,p) row; 1025 complex outputs per row, packed as
// one uint32 per bin: LOW half = im, HIGH half = re (element 2k = im,
// 2k+1 = re) -- layout determined empirically from the 24.39-signature
// error in R3 (swapped-halves Mobius-circle bound c + r*sqrt(2) matched
// observed 24.34375 to 0.2%).
//
// theta_k = pi*k/1024, h = theta/2 = pi*k/2048 in [0, pi/2].
// H(theta) = (d + i*g1*s) / (d + i*g2*s)
//   d  = cos(theta) - cos(w0) = 2*(sin^2(w0/2) - sin^2(h))   [product form]
//   s  = sin(theta) = 2*sin(h)*cos(h)
//   g1 = alpha*A, g2 = alpha/A, alpha = sin(w0)/(2q), A = 10^(gain/40)
// => re = (d^2 + alpha^2 s^2) / (d^2 + g2^2 s^2)      [g1*g2 = alpha^2]
//    im = (g1 - g2) * s * d   / (d^2 + g2^2 s^2)
__global__ __launch_bounds__(256) void eq_kernel(
    const float* __restrict__ center,
    const float* __restrict__ gain,
    const float* __restrict__ q,
    unsigned int* __restrict__ out)
{
    __shared__ float p[4];
    const int row = blockIdx.x;
    if (threadIdx.x == 0) {
        float w0 = 1.4247585730565955e-4f * center[row];   // 2*pi/44100
        float sh, ch;
        sincosf(0.5f * w0, &sh, &ch);                      // sin/cos of w0/2
        float A = exp2f(0.08304820237218406f * gain[row]); // 10^(gain/40)
        float alpha = sh * ch / q[row];                    // sin(w0)/(2q)
        float g2 = alpha / A;
        p[0] = sh;
        p[1] = alpha * alpha;        // g1*g2
        p[2] = g2;
        p[3] = alpha * A - g2;       // g1 - g2
    }
    __syncthreads();
    const float sh = p[0], a2 = p[1], g2 = p[2], gd = p[3];

    unsigned int* __restrict__ orow = out + (size_t)row * NBINS;
    for (int k = threadIdx.x; k < NBINS; k += 256) {
        float h = (float)k * 1.5339807878856412e-3f;  // pi/2048
        float st, ct;
        sincosf(h, &st, &ct);        // sin(theta/2), cos(theta/2)
        float d  = 2.0f * (sh - st) * (sh + st);
        float s  = 2.0f * st * ct;
        float d2 = d * d;
        float g2s = g2 * s;
        float den = fmaf(g2s, g2s, d2);
        float inv = __builtin_amdgcn_rcpf(den);
        float re = fmaf(a2, s * s, d2) * inv;
        float im = gd * s * d * inv;
        orow[k] = f2bf(im) | (f2bf(re) << 16);  // im low (elem 2k), re high (2k+1)
    }
}

extern "C" void kernel_launch(void* const* d_in, const int* in_sizes, int n_in,
                              void* d_out, int out_size, void* d_ws, size_t ws_size,
                              hipStream_t stream) {
    const float* center = (const float*)d_in[0];
    const float* gain   = (const float*)d_in[1];
    const float* q      = (const float*)d_in[2];
    eq_kernel<<<NROWS, 256, 0, stream>>>(center, gain, q, (unsigned int*)d_out);
}

// Round 5
// 115.306 us; speedup vs baseline: 1.1780x; 1.1780x over previous
//
#include <hip/hip_runtime.h>
#include <math.h>

constexpr int NBINS = 1025;              // 2048/2 + 1
constexpr int NROWS = 128 * 192;         // B * P
constexpr int RPB   = 16;                // rows per block
constexpr int NBLK  = NROWS / RPB;       // 1536 blocks
constexpr int DWB   = RPB * NBINS;       // 16400 dwords per block
constexpr int QPB   = DWB / 4;           // 4100 uint4 stores per block (exact)

// Round-to-nearest-even float -> bf16 (finite inputs only).
__device__ inline unsigned int f2bf(float f) {
    unsigned int u = __float_as_uint(f);
    return (u + 0x7FFFu + ((u >> 16) & 1u)) >> 16;
}

// Output layout (empirically determined, R3/R4): per bin one uint32,
// LOW half = im (flat elem 2k), HIGH half = re (flat elem 2k+1), bf16 RNE.
//
// H(theta) = (d + i*g1*s)/(d + i*g2*s), theta = pi*k/1024, h = theta/2:
//   d  = cos(theta)-cos(w0) = 2*(sin^2(w0/2) - sin^2(h))   [product form]
//   s  = sin(theta) = 2*sin(h)*cos(h)
//   g1 = alpha*A, g2 = alpha/A, alpha = sin(w0)/(2q), A = 10^(gain/40)
//   re = (d^2 + alpha^2 s^2)/(d^2 + g2^2 s^2)   [g1*g2 = alpha^2]
//   im = (g1-g2)*s*d        /(d^2 + g2^2 s^2)
//
// 16 rows/block: shared theta-table built once per block (16x fewer sincosf),
// main loop = LDS reads + FMAs + packed 16B stores. Block base is 16B-aligned
// (16400 dwords = 65600 B), so the odd 1025-dword row length never misaligns.
__global__ __launch_bounds__(256) void eq_kernel(
    const float* __restrict__ center,
    const float* __restrict__ gain,
    const float* __restrict__ q,
    unsigned int* __restrict__ out)
{
    __shared__ float2 tab[NBINS];        // (sin(h), cos(h)) per bin
    __shared__ float4 rp[RPB];           // (sh, alpha^2, g2, g1-g2) per row

    const int tid = threadIdx.x;
    if (tid < RPB) {
        const int row = blockIdx.x * RPB + tid;
        float w0 = 1.4247585730565955e-4f * center[row];   // 2*pi/44100
        float sh, ch;
        sincosf(0.5f * w0, &sh, &ch);                      // sin/cos of w0/2
        float A = exp2f(0.08304820237218406f * gain[row]); // 10^(gain/40)
        float alpha = sh * ch / q[row];                    // sin(w0)/(2q)
        float g2 = alpha / A;
        rp[tid] = make_float4(sh, alpha * alpha, g2, alpha * A - g2);
    }
    for (int k = tid; k < NBINS; k += 256) {
        float st, ct;
        sincosf((float)k * 1.5339807878856412e-3f, &st, &ct); // pi/2048
        tab[k] = make_float2(st, ct);
    }
    __syncthreads();

    uint4* __restrict__ ob = (uint4*)(out + (size_t)blockIdx.x * DWB);
    for (int g = tid; g < QPB; g += 256) {
        const int f0 = 4 * g;
        unsigned int w[4];
        #pragma unroll
        for (int j = 0; j < 4; ++j) {
            const int f = f0 + j;
            const int r = f / NBINS;               // 0..15 (magic-mul)
            const int k = f - r * NBINS;
            const float4 P = rp[r];                // mostly wave-uniform -> broadcast
            const float2 t = tab[k];
            float d  = 2.0f * (P.x - t.x) * (P.x + t.x);
            float s  = 2.0f * t.x * t.y;
            float d2 = d * d;
            float g2s = P.z * s;
            float den = fmaf(g2s, g2s, d2);
            float inv = __builtin_amdgcn_rcpf(den);
            float re = fmaf(P.y, s * s, d2) * inv;
            float im = P.w * s * d * inv;
            w[j] = f2bf(im) | (f2bf(re) << 16);    // im low (2k), re high (2k+1)
        }
        ob[g] = make_uint4(w[0], w[1], w[2], w[3]);
    }
}

extern "C" void kernel_launch(void* const* d_in, const int* in_sizes, int n_in,
                              void* d_out, int out_size, void* d_ws, size_t ws_size,
                              hipStream_t stream) {
    const float* center = (const float*)d_in[0];
    const float* gain   = (const float*)d_in[1];
    const float* q      = (const float*)d_in[2];
    eq_kernel<<<NBLK, 256, 0, stream>>>(center, gain, q, (unsigned int*)d_out);
}

// Round 6
// 112.398 us; speedup vs baseline: 1.2085x; 1.0259x over previous
//
#include <hip/hip_runtime.h>
#include <math.h>

constexpr int NBINS = 1025;              // 2048/2 + 1
constexpr int NROWS = 128 * 192;         // B * P
constexpr int RPB   = 16;                // rows per block (4 per wave)
constexpr int NBLK  = NROWS / RPB;       // 1536 blocks

// Round-to-nearest-even float -> bf16 (finite inputs only).
__device__ inline unsigned int f2bf(float f) {
    unsigned int u = __float_as_uint(f);
    return (u + 0x7FFFu + ((u >> 16) & 1u)) >> 16;
}

// Output layout (empirical, R3/R4): one uint32 per bin, LOW half = im
// (flat elem 2k), HIGH half = re (flat elem 2k+1), bf16 RNE.
//
// H(theta) = (d + i*g1*s)/(d + i*g2*s), theta = pi*k/1024, h = theta/2.
// Product form (cancellation-safe near resonance — required, see R5 notes):
//   d  = 2*(sh - st)*(sh + st),  sh = sin(w0/2), st = sin(h)
//   s  = sin(theta) = 2*sin(h)*cos(h)   [stored in table]
// With dp = (sh-st)(sh+st)  (d = 2*dp), divide num/den by 4:
//   re = (dp^2 + (a^2/4) s^2) / (dp^2 + (g2^2/4) s^2)
//   im = ((g1-g2)/2) * s * dp / (dp^2 + (g2^2/4) s^2)
// Row consts: P = (sh, A2=alpha^2/4, G2=g2^2/4, GD=(g1-g2)/2).
//
// Structure: wave-per-row. Each wave owns 4 rows; lane handles bin
// k = lane + 64*i (i<16) -> tab reads stride 8 B (2-way, free), row params
// wave-uniform (LDS broadcast), no per-bin div. k=1024 is exactly H=1.
__global__ __launch_bounds__(256) void eq_kernel(
    const float* __restrict__ center,
    const float* __restrict__ gain,
    const float* __restrict__ q,
    unsigned int* __restrict__ out)
{
    __shared__ float2 tab[1024];         // (sin(h), sin(theta)) for k=0..1023
    __shared__ float4 rp[RPB];           // (sh, A2, G2, GD) per row

    const int tid  = threadIdx.x;
    const int wave = tid >> 6;
    const int lane = tid & 63;

    if (tid < RPB) {
        const int row = blockIdx.x * RPB + tid;
        float w0 = 1.4247585730565955e-4f * center[row];   // 2*pi/44100
        float sh, ch;
        sincosf(0.5f * w0, &sh, &ch);                      // sin/cos of w0/2
        float A = exp2f(0.08304820237218406f * gain[row]); // 10^(gain/40)
        float alpha = sh * ch / q[row];                    // sin(w0)/(2q)
        float g2 = alpha / A;
        float gd = alpha * A - g2;                         // g1 - g2
        rp[tid] = make_float4(sh, 0.25f * alpha * alpha, 0.25f * g2 * g2, 0.5f * gd);
    }
    for (int k = tid; k < 1024; k += 256) {
        float st, ct;
        sincosf((float)k * 1.5339807878856412e-3f, &st, &ct); // h = pi*k/2048
        tab[k] = make_float2(st, 2.0f * st * ct);             // (sin h, sin theta)
    }
    __syncthreads();

    const int rbase = blockIdx.x * RPB + wave * 4;
    for (int j = 0; j < 4; ++j) {
        const int row = rbase + j;
        const float4 P = rp[wave * 4 + j];     // wave-uniform -> LDS broadcast
        unsigned int* __restrict__ orow = out + (size_t)row * NBINS;
        #pragma unroll
        for (int i = 0; i < 16; ++i) {
            const int k = lane + (i << 6);
            const float2 t = tab[k];           // stride-8B: conflict-free
            float u  = P.x - t.x;
            float v  = P.x + t.x;
            float dp = u * v;
            float D2 = dp * dp;
            float S2 = t.y * t.y;
            float den = fmaf(P.z, S2, D2);
            float inv = __builtin_amdgcn_rcpf(den);
            float re = fmaf(P.y, S2, D2) * inv;
            float im = P.w * t.y * dp * inv;
            orow[k] = f2bf(im) | (f2bf(re) << 16);  // im low (2k), re high (2k+1)
        }
    }
    // k = 1024 (theta = pi): H = 1 exactly -> re=1, im=0 -> 0x3F800000
    if (tid < RPB)
        out[(size_t)(blockIdx.x * RPB + tid) * NBINS + 1024] = 0x3F800000u;
}

extern "C" void kernel_launch(void* const* d_in, const int* in_sizes, int n_in,
                              void* d_out, int out_size, void* d_ws, size_t ws_size,
                              hipStream_t stream) {
    const float* center = (const float*)d_in[0];
    const float* gain   = (const float*)d_in[1];
    const float* q      = (const float*)d_in[2];
    eq_kernel<<<NBLK, 256, 0, stream>>>(center, gain, q, (unsigned int*)d_out);
}

// Round 7
// 110.694 us; speedup vs baseline: 1.2271x; 1.0154x over previous
//
#include <hip/hip_runtime.h>
#include <math.h>

constexpr int NBINS = 1025;              // 2048/2 + 1
constexpr int NROWS = 128 * 192;         // B * P
constexpr int RPB   = 16;                // rows per block (4 per wave)
constexpr int NBLK  = NROWS / RPB;       // 1536 blocks = 6/CU, fully resident

// Round-to-nearest-even float -> bf16 (finite inputs only).
__device__ inline unsigned int f2bf(float f) {
    unsigned int u = __float_as_uint(f);
    return (u + 0x7FFFu + ((u >> 16) & 1u)) >> 16;
}

// Output layout (empirical, R3/R4): one uint32 per bin, LOW half = im
// (flat elem 2k), HIGH half = re (flat elem 2k+1), bf16 RNE.
//
// H(theta) = (d + i*g1*s)/(d + i*g2*s), theta = pi*k/1024, h = theta/2.
// Product form (cancellation-safe near resonance):
//   dp = (sh - st)(sh + st),  sh = sin(w0/2), st = sin(h); d = 2*dp
//   s  = sin(theta) = 2*sin(h)*cos(h)   [tab stores (st, s)]
//   re = (dp^2 + (a^2/4) s^2) / (dp^2 + (g2^2/4) s^2)
//   im = ((g1-g2)/2)*s*dp     / (dp^2 + (g2^2/4) s^2)
// Row consts P = (sh, alpha^2/4, g2^2/4, (g1-g2)/2).
//
// Store-width trick (R7): rows are 1025 dwords, so row base byte = 4100*row
// is 8B-aligned iff row even; base+4 is 8B-aligned iff row odd. Pair bins
// (k,k+1) from koff=row&1 -> 512 aligned dwordx2 stores covering 1024 bins;
// the leftover bin (k=1024 even rows / k=0 odd rows) is exactly H=1
// (num==den at theta=0 and pi) -> constant 0x3F800000.
__global__ __launch_bounds__(256) void eq_kernel(
    const float* __restrict__ center,
    const float* __restrict__ gain,
    const float* __restrict__ q,
    unsigned int* __restrict__ out)
{
    __shared__ float2 tab[NBINS];        // (sin h, sin theta), k = 0..1024
    __shared__ float4 rp[RPB];           // (sh, A2, G2, GD) per row

    const int tid  = threadIdx.x;
    const int wave = tid >> 6;
    const int lane = tid & 63;

    if (tid < RPB) {
        const int row = blockIdx.x * RPB + tid;
        float w0 = 1.4247585730565955e-4f * center[row];   // 2*pi/44100
        float sh, ch;
        sincosf(0.5f * w0, &sh, &ch);                      // sin/cos of w0/2
        float A = exp2f(0.08304820237218406f * gain[row]); // 10^(gain/40)
        float alpha = sh * ch / q[row];                    // sin(w0)/(2q)
        float g2 = alpha / A;
        float gd = alpha * A - g2;                         // g1 - g2
        rp[tid] = make_float4(sh, 0.25f * alpha * alpha, 0.25f * g2 * g2, 0.5f * gd);
    }
    for (int k = tid; k < NBINS; k += 256) {
        float st, ct;
        sincosf((float)k * 1.5339807878856412e-3f, &st, &ct); // h = pi*k/2048
        tab[k] = make_float2(st, 2.0f * st * ct);             // (sin h, sin theta)
    }
    __syncthreads();

    for (int j = 0; j < 4; ++j) {
        const int r   = wave * 4 + j;          // row within block
        const int row = blockIdx.x * RPB + r;
        const float4 P = rp[r];                // wave-uniform -> LDS broadcast
        const int koff = row & 1;
        unsigned int* __restrict__ orow = out + (size_t)row * NBINS;
        uint2* __restrict__ op = (uint2*)(orow + koff);   // 8B-aligned by parity
        if (lane == 0)
            orow[koff ? 0 : 1024] = 0x3F800000u;          // H = 1 exactly
        #pragma unroll
        for (int i = 0; i < 8; ++i) {
            const int k = koff + 2 * lane + (i << 7);
            const float2 t0 = tab[k];
            const float2 t1 = tab[k + 1];      // merges into one 16B LDS access
            float dp0 = (P.x - t0.x) * (P.x + t0.x);
            float dp1 = (P.x - t1.x) * (P.x + t1.x);
            float D20 = dp0 * dp0,  D21 = dp1 * dp1;
            float S20 = t0.y * t0.y, S21 = t1.y * t1.y;
            float i0 = __builtin_amdgcn_rcpf(fmaf(P.z, S20, D20));
            float i1 = __builtin_amdgcn_rcpf(fmaf(P.z, S21, D21));
            float re0 = fmaf(P.y, S20, D20) * i0;
            float re1 = fmaf(P.y, S21, D21) * i1;
            float im0 = P.w * t0.y * dp0 * i0;
            float im1 = P.w * t1.y * dp1 * i1;
            op[lane + (i << 6)] = make_uint2(f2bf(im0) | (f2bf(re0) << 16),
                                             f2bf(im1) | (f2bf(re1) << 16));
        }
    }
}

extern "C" void kernel_launch(void* const* d_in, const int* in_sizes, int n_in,
                              void* d_out, int out_size, void* d_ws, size_t ws_size,
                              hipStream_t stream) {
    const float* center = (const float*)d_in[0];
    const float* gain   = (const float*)d_in[1];
    const float* q      = (const float*)d_in[2];
    eq_kernel<<<NBLK, 256, 0, stream>>>(center, gain, q, (unsigned int*)d_out);
}